// Round 1
// baseline (352.364 us; speedup 1.0000x reference)
//
#include <hip/hip_runtime.h>

#define D 64
#define KP 50          // neighbors per row
#define STR 68         // padded LDS k-stride (multiple of 4 for float4)
#define NITEMS 10000   // R row stride

struct SM {
  float XA[D * STR];   // input, transposed: XA[j][k]
  float XB[D * STR];   // gate output, transposed: XB[d][k]
  float sp[D * 17];    // attention-score partials [k][dq]
  float init[D];       // per-d init for matmul (bias / bias+ctxv)
  float ctx[D];
  float a[D];          // softmax weights
  float v[D];          // attention-weighted sum
  float buf0[D];
  float buf1[D];
  float cat[2 * D];
  float part[4 * D];   // matvec partials
  int   ci[KP];
  int   rk[KP];
};

// ---- 64x64x64 tile core: acc[i][j] += XA[j][k0+i] * W[j][d0+j'] ----
__device__ inline void mm_core(const float* XA, const float* W, int k0, int d0,
                               float acc[4][4]) {
  const float* xp = XA + k0;
  const float* wp = W + d0;
#pragma unroll 4
  for (int j = 0; j < D; ++j) {
    float4 xv = *(const float4*)xp;
    float4 wv = *(const float4*)wp;
    float xr[4] = {xv.x, xv.y, xv.z, xv.w};
    float wr[4] = {wv.x, wv.y, wv.z, wv.w};
#pragma unroll
    for (int i = 0; i < 4; ++i)
#pragma unroll
      for (int jj = 0; jj < 4; ++jj)
        acc[i][jj] = fmaf(xr[i], wr[jj], acc[i][jj]);
    xp += STR;
    wp += D;
  }
}

// Y^T[d][k] = relu(init[d] + oprow[rk[k]][d] + sum_j XA[j][k]*W[j][d])
__device__ inline void block_mm_relu(SM& sm, const float* XA, float* YT,
                                     const float* W, const float* oprow) {
  const int t = threadIdx.x;
  const int k0 = (t >> 4) * 4;
  const int d0 = (t & 15) * 4;
  float acc[4][4];
#pragma unroll
  for (int i = 0; i < 4; ++i)
#pragma unroll
    for (int jj = 0; jj < 4; ++jj) acc[i][jj] = sm.init[d0 + jj];
  if (oprow) {
#pragma unroll
    for (int i = 0; i < 4; ++i) {
      int k = k0 + i;
      if (k < KP) {
        const float* op = &oprow[sm.rk[k] * D + d0];
#pragma unroll
        for (int jj = 0; jj < 4; ++jj) acc[i][jj] += op[jj];
      }
    }
  }
  mm_core(XA, W, k0, d0, acc);
#pragma unroll
  for (int jj = 0; jj < 4; ++jj) {
    float4 o;
    o.x = fmaxf(acc[0][jj], 0.f);
    o.y = fmaxf(acc[1][jj], 0.f);
    o.z = fmaxf(acc[2][jj], 0.f);
    o.w = fmaxf(acc[3][jj], 0.f);
    *(float4*)&YT[(d0 + jj) * STR + k0] = o;
  }
}

// attention: h[k][d]=relu(init[d]+sum_j XA[j][k]*Wa1x[j][d]);
// sp[k][dq] = sum over this thread's 4 d of h*Wa2[d]  (ba2 dropped: softmax-invariant)
__device__ inline void block_mm_att(SM& sm, const float* XA, const float* Wa1,
                                    const float* Wa2) {
  const int t = threadIdx.x;
  const int k0 = (t >> 4) * 4;
  const int d0 = (t & 15) * 4;
  float acc[4][4];
#pragma unroll
  for (int i = 0; i < 4; ++i)
#pragma unroll
    for (int jj = 0; jj < 4; ++jj) acc[i][jj] = sm.init[d0 + jj];
  mm_core(XA, Wa1, k0, d0, acc);
  float4 w2 = *(const float4*)&Wa2[d0];
#pragma unroll
  for (int i = 0; i < 4; ++i) {
    float s = fmaxf(acc[i][0], 0.f) * w2.x + fmaxf(acc[i][1], 0.f) * w2.y +
              fmaxf(acc[i][2], 0.f) * w2.z + fmaxf(acc[i][3], 0.f) * w2.w;
    sm.sp[(k0 + i) * 17 + (t & 15)] = s;
  }
}

__device__ inline void softmax_s(SM& sm) {
  __syncthreads();
  if (threadIdx.x < D) {
    const int k = threadIdx.x;
    float s = 0.f;
#pragma unroll
    for (int q = 0; q < 16; ++q) s += sm.sp[k * 17 + q];
    float val = (k < KP) ? s : -1e30f;
    float m = val;
#pragma unroll
    for (int o = 1; o < 64; o <<= 1) m = fmaxf(m, __shfl_xor(m, o, 64));
    float e = (k < KP) ? __expf(val - m) : 0.f;
    float sum = e;
#pragma unroll
    for (int o = 1; o < 64; o <<= 1) sum += __shfl_xor(sum, o, 64);
    sm.a[k] = e / sum;
  }
  __syncthreads();
}

// v[d] = sum_k a[k] * X[d][k]
__device__ inline void weighted_sum(SM& sm, const float* X) {
  if (threadIdx.x < D) {
    const int d = threadIdx.x;
    float acc = 0.f;
    for (int k = 0; k < KP; ++k) acc = fmaf(sm.a[k], X[d * STR + k], acc);
    sm.v[d] = acc;
  }
  __syncthreads();
}

// y[d] = act(bias[d] + sum_{j<J} xin[j]*W[j][d]); 256 threads, partial-split over j
template <int J, bool RELU>
__device__ inline void mv(SM& sm, const float* xin, float* y, const float* W,
                          const float* bias) {
  const int w = threadIdx.x >> 6, d = threadIdx.x & 63;
  const int JW = J / 4;
  float p = 0.f;
  const float* xw = &xin[w * JW];
  const float* Wp = &W[(w * JW) * D + d];
  for (int j = 0; j < JW; ++j) {
    p = fmaf(xw[j], *Wp, p);
    Wp += D;
  }
  sm.part[w * D + d] = p;
  __syncthreads();
  if (threadIdx.x < D) {
    float s = bias[d] + sm.part[d] + sm.part[D + d] + sm.part[2 * D + d] +
              sm.part[3 * D + d];
    y[d] = RELU ? fmaxf(s, 0.f) : s;
  }
  __syncthreads();
}

// XA[j][k] = src[idx[k]*D + j], coalesced loads, transposed store
__device__ inline void load_rows_T(SM& sm, const float* src, const int* idx, int n) {
  const int w = threadIdx.x >> 6, j = threadIdx.x & 63;
  for (int k = w; k < n; k += 4) sm.XA[j * STR + k] = src[idx[k] * D + j];
}

__device__ inline void zero_pad(SM& sm) {
  for (int idx = threadIdx.x; idx < D * (64 - KP); idx += 256) {
    int j = idx / (64 - KP), k = KP + idx % (64 - KP);
    sm.XA[j * STR + k] = 0.f;
  }
}

// ---------------- kernel 0: opinion tables op[r] = opinion_emb[r] @ Wg[64:] -----
__global__ __launch_bounds__(64) void k_op(const float* opinion_emb,
                                           const float* ia_Wg, const float* ua_Wg,
                                           float* op_ia, float* op_ua) {
  const int r = blockIdx.x % 5;
  const bool ua = blockIdx.x >= 5;
  const float* Wg = ua ? ua_Wg : ia_Wg;
  float* o = ua ? op_ua : op_ia;
  const int d = threadIdx.x;
  float acc = 0.f;
  for (int j = 0; j < D; ++j)
    acc = fmaf(opinion_emb[r * D + j], Wg[(D + j) * D + d], acc);
  o[r * D + d] = acc;
}

// ---------------- kernel 1: h_I_all for every user ------------------------------
__global__ __launch_bounds__(256) void k_hIall(
    const int* C, const int* Rm, const float* user_emb, const float* item_emb,
    const float* ia_Wg, const float* ia_bg, const float* ia_Wa1,
    const float* ia_ba1, const float* ia_Wa2, const float* ia_W,
    const float* ia_b, const float* op_ia, float* h_I_all) {
  __shared__ SM sm;
  const int u = blockIdx.x;
  const int t = threadIdx.x;
  if (t < KP) {
    int c = C[u * KP + t];
    sm.ci[t] = c;
    sm.rk[t] = Rm[u * NITEMS + c];
  }
  if (t < D) sm.ctx[t] = user_emb[u * D + t];
  __syncthreads();
  load_rows_T(sm, item_emb, sm.ci, KP);
  zero_pad(sm);
  if (t < D) sm.init[t] = ia_bg[t];
  __syncthreads();
  block_mm_relu(sm, sm.XA, sm.XB, ia_Wg, op_ia);   // x^T in XB
  __syncthreads();
  mv<D, false>(sm, sm.ctx, sm.init, &ia_Wa1[D * D], ia_ba1);  // init = ba1 + ctx@Wa1[64:]
  block_mm_att(sm, sm.XB, ia_Wa1, ia_Wa2);
  softmax_s(sm);
  weighted_sum(sm, sm.XB);
  mv<D, true>(sm, sm.v, sm.buf0, ia_W, ia_b);
  if (t < D) h_I_all[u * D + t] = sm.buf0[t];
}

// ---------------- kernel 2: h_S (social aggregation) ----------------------------
__global__ __launch_bounds__(256) void k_hS(
    const int* user_idx, const int* Nn, const float* user_emb,
    const float* sa_Wa1, const float* sa_ba1, const float* sa_Wa2,
    const float* sa_W, const float* sa_b, const float* h_I_all, float* h_S) {
  __shared__ SM sm;
  const int b = blockIdx.x, t = threadIdx.x;
  const int u = user_idx[b];
  if (t < KP) sm.ci[t] = Nn[u * KP + t];
  if (t < D) sm.ctx[t] = user_emb[u * D + t];
  __syncthreads();
  load_rows_T(sm, h_I_all, sm.ci, KP);
  zero_pad(sm);
  __syncthreads();
  mv<D, false>(sm, sm.ctx, sm.init, &sa_Wa1[D * D], sa_ba1);
  block_mm_att(sm, sm.XA, sa_Wa1, sa_Wa2);
  softmax_s(sm);
  weighted_sum(sm, sm.XA);
  mv<D, true>(sm, sm.v, sm.buf0, sa_W, sa_b);
  if (t < D) h_S[b * D + t] = sm.buf0[t];
}

// ---------------- kernel 3: z (item-side agg) + fu/rp MLPs → output -------------
__global__ __launch_bounds__(256) void k_z_mlp(
    const int* user_idx, const int* item_idx, const int* Bm, const int* Rm,
    const float* user_emb, const float* item_emb, const float* ua_Wg,
    const float* ua_bg, const float* ua_Wa1, const float* ua_ba1,
    const float* ua_Wa2, const float* ua_W, const float* ua_b,
    const float* op_ua, const float* fu_W1, const float* fu_b1,
    const float* fu_W2, const float* fu_b2, const float* fu_W3,
    const float* fu_b3, const float* rp_W1, const float* rp_b1,
    const float* rp_W2, const float* rp_b2, const float* rp_W3,
    const float* rp_b3, const float* h_I_all, const float* h_S, float* out) {
  __shared__ SM sm;
  const int b = blockIdx.x, t = threadIdx.x;
  const int it = item_idx[b];
  const int u = user_idx[b];
  if (t < KP) {
    int bn = Bm[it * KP + t];
    sm.ci[t] = bn;
    sm.rk[t] = Rm[bn * NITEMS + it];
  }
  if (t < D) sm.ctx[t] = item_emb[it * D + t];
  __syncthreads();
  load_rows_T(sm, user_emb, sm.ci, KP);
  zero_pad(sm);
  if (t < D) sm.init[t] = ua_bg[t];
  __syncthreads();
  block_mm_relu(sm, sm.XA, sm.XB, ua_Wg, op_ua);  // f^T in XB
  __syncthreads();
  mv<D, false>(sm, sm.ctx, sm.init, &ua_Wa1[D * D], ua_ba1);
  block_mm_att(sm, sm.XB, ua_Wa1, ua_Wa2);
  softmax_s(sm);
  weighted_sum(sm, sm.XB);
  mv<D, true>(sm, sm.v, sm.buf1, ua_W, ua_b);  // z in buf1
  // ---- fu MLP: h = relu3(concat(h_I_all[u], h_S[b]) @ fu_*) ----
  if (t < D) {
    sm.cat[t] = h_I_all[u * D + t];
    sm.cat[D + t] = h_S[b * D + t];
  }
  __syncthreads();
  mv<2 * D, true>(sm, sm.cat, sm.buf0, fu_W1, fu_b1);
  mv<D, true>(sm, sm.buf0, sm.v, fu_W2, fu_b2);
  mv<D, true>(sm, sm.v, sm.buf0, fu_W3, fu_b3);
  // ---- rp MLP on concat(h, z) ----
  if (t < D) {
    sm.cat[t] = sm.buf0[t];
    sm.cat[D + t] = sm.buf1[t];
  }
  __syncthreads();
  mv<2 * D, true>(sm, sm.cat, sm.buf0, rp_W1, rp_b1);
  mv<D, true>(sm, sm.buf0, sm.v, rp_W2, rp_b2);
  if (t < D) {
    float p = sm.v[t] * rp_W3[t];
#pragma unroll
    for (int o = 1; o < 64; o <<= 1) p += __shfl_xor(p, o, 64);
    if (t == 0) out[b] = p + rp_b3[0];
  }
}

extern "C" void kernel_launch(void* const* d_in, const int* in_sizes, int n_in,
                              void* d_out, int out_size, void* d_ws,
                              size_t ws_size, hipStream_t stream) {
  const int* user_idx = (const int*)d_in[0];
  const int* item_idx = (const int*)d_in[1];
  const int* C = (const int*)d_in[2];
  const int* Nn = (const int*)d_in[3];
  const int* Bm = (const int*)d_in[4];
  const int* Rm = (const int*)d_in[5];
  const float* user_emb = (const float*)d_in[6];
  const float* item_emb = (const float*)d_in[7];
  const float* opinion_emb = (const float*)d_in[8];
  const float* ia_Wg = (const float*)d_in[9];
  const float* ia_bg = (const float*)d_in[10];
  const float* ua_Wg = (const float*)d_in[11];
  const float* ua_bg = (const float*)d_in[12];
  const float* ia_Wa1 = (const float*)d_in[13];
  const float* ia_ba1 = (const float*)d_in[14];
  const float* ia_Wa2 = (const float*)d_in[15];
  const float* ia_W = (const float*)d_in[17];
  const float* ia_b = (const float*)d_in[18];
  const float* sa_Wa1 = (const float*)d_in[19];
  const float* sa_ba1 = (const float*)d_in[20];
  const float* sa_Wa2 = (const float*)d_in[21];
  const float* sa_W = (const float*)d_in[23];
  const float* sa_b = (const float*)d_in[24];
  const float* ua_Wa1 = (const float*)d_in[25];
  const float* ua_ba1 = (const float*)d_in[26];
  const float* ua_Wa2 = (const float*)d_in[27];
  const float* ua_W = (const float*)d_in[29];
  const float* ua_b = (const float*)d_in[30];
  const float* fu_W1 = (const float*)d_in[31];
  const float* fu_b1 = (const float*)d_in[32];
  const float* fu_W2 = (const float*)d_in[33];
  const float* fu_b2 = (const float*)d_in[34];
  const float* rp_W1 = (const float*)d_in[35];
  const float* rp_b1 = (const float*)d_in[36];
  const float* rp_W2 = (const float*)d_in[37];
  const float* rp_b2 = (const float*)d_in[38];
  const float* fu_W3 = (const float*)d_in[39];
  const float* fu_b3 = (const float*)d_in[40];
  const float* rp_W3 = (const float*)d_in[41];
  const float* rp_b3 = (const float*)d_in[42];

  const int NU = in_sizes[6] / D;  // 10000 users
  const int B = in_sizes[0];       // 2048

  float* ws = (float*)d_ws;
  float* h_I_all = ws;               // NU*D
  float* h_S = ws + (size_t)NU * D;  // B*D
  float* op_ia = h_S + (size_t)B * D;
  float* op_ua = op_ia + 5 * D;

  k_op<<<10, 64, 0, stream>>>(opinion_emb, ia_Wg, ua_Wg, op_ia, op_ua);
  k_hIall<<<NU, 256, 0, stream>>>(C, Rm, user_emb, item_emb, ia_Wg, ia_bg,
                                  ia_Wa1, ia_ba1, ia_Wa2, ia_W, ia_b, op_ia,
                                  h_I_all);
  k_hS<<<B, 256, 0, stream>>>(user_idx, Nn, user_emb, sa_Wa1, sa_ba1, sa_Wa2,
                              sa_W, sa_b, h_I_all, h_S);
  k_z_mlp<<<B, 256, 0, stream>>>(user_idx, item_idx, Bm, Rm, user_emb, item_emb,
                                 ua_Wg, ua_bg, ua_Wa1, ua_ba1, ua_Wa2, ua_W,
                                 ua_b, op_ua, fu_W1, fu_b1, fu_W2, fu_b2, fu_W3,
                                 fu_b3, rp_W1, rp_b1, rp_W2, rp_b2, rp_W3,
                                 rp_b3, h_I_all, h_S, (float*)d_out);
}

// Round 2
// 281.526 us; speedup vs baseline: 1.2516x; 1.2516x over previous
//
#include <hip/hip_runtime.h>

#define D 64
#define KP 50          // neighbors per row
#define STR 68         // padded LDS row stride (floats, multiple of 4)
#define NITEMS 10000   // R row stride

struct SM {
  float X[D * STR];    // row-major: X[k][j], reused in place for gate output
  float init[D];       // per-d init for matmul (bias / bias+ctx@Wa1hi)
  float ctx[D];
  float a[D];          // attention scores -> weights
  float v[D];          // attention-weighted sum
  float buf0[D];
  float buf1[D];
  float cat[2 * D];
  float part[4 * D];   // matvec / weighted-sum partials
  int   ci[D];
  int   rk[D];
};

// acc[ki][dj] += sum_j X[k0+ki][j] * W[j][d0+dj]
__device__ inline void mm_core(const float* X, const float* __restrict__ W,
                               int k0, int d0, float acc[4][4]) {
#pragma unroll 2
  for (int j4 = 0; j4 < D; j4 += 4) {
    float4 xv[4], wv[4];
#pragma unroll
    for (int ki = 0; ki < 4; ++ki)
      xv[ki] = *(const float4*)&X[(k0 + ki) * STR + j4];
#pragma unroll
    for (int jj = 0; jj < 4; ++jj)
      wv[jj] = *(const float4*)&W[(j4 + jj) * D + d0];
#pragma unroll
    for (int ki = 0; ki < 4; ++ki) {
      const float xr[4] = {xv[ki].x, xv[ki].y, xv[ki].z, xv[ki].w};
#pragma unroll
      for (int jj = 0; jj < 4; ++jj) {
        acc[ki][0] = fmaf(xr[jj], wv[jj].x, acc[ki][0]);
        acc[ki][1] = fmaf(xr[jj], wv[jj].y, acc[ki][1]);
        acc[ki][2] = fmaf(xr[jj], wv[jj].z, acc[ki][2]);
        acc[ki][3] = fmaf(xr[jj], wv[jj].w, acc[ki][3]);
      }
    }
  }
}

// X <- relu(init + op[rk[k]] + X @ W)  (in place, row-major)
__device__ inline void gate_mm_inplace(SM& sm, const float* __restrict__ W,
                                       const float* __restrict__ oprow) {
  const int t = threadIdx.x;
  const int k0 = (t >> 4) * 4, d0 = (t & 15) * 4;
  float acc[4][4];
#pragma unroll
  for (int ki = 0; ki < 4; ++ki)
#pragma unroll
    for (int jj = 0; jj < 4; ++jj) acc[ki][jj] = sm.init[d0 + jj];
#pragma unroll
  for (int ki = 0; ki < 4; ++ki) {
    int k = k0 + ki;
    if (k < KP) {
      const float4 op = *(const float4*)&oprow[sm.rk[k] * D + d0];
      acc[ki][0] += op.x; acc[ki][1] += op.y;
      acc[ki][2] += op.z; acc[ki][3] += op.w;
    }
  }
  mm_core(sm.X, W, k0, d0, acc);
  __syncthreads();               // all reads of X done
#pragma unroll
  for (int ki = 0; ki < 4; ++ki) {
    float4 o;
    o.x = fmaxf(acc[ki][0], 0.f);
    o.y = fmaxf(acc[ki][1], 0.f);
    o.z = fmaxf(acc[ki][2], 0.f);
    o.w = fmaxf(acc[ki][3], 0.f);
    *(float4*)&sm.X[(k0 + ki) * STR + d0] = o;
  }
  __syncthreads();
}

// raw scores into sm.a[k]; h never materialized (ba2 softmax-invariant, dropped)
__device__ inline void att_mm(SM& sm, const float* __restrict__ Wa1,
                              const float* __restrict__ Wa2) {
  const int t = threadIdx.x;
  const int k0 = (t >> 4) * 4, d0 = (t & 15) * 4;
  float acc[4][4];
#pragma unroll
  for (int ki = 0; ki < 4; ++ki)
#pragma unroll
    for (int jj = 0; jj < 4; ++jj) acc[ki][jj] = sm.init[d0 + jj];
  mm_core(sm.X, Wa1, k0, d0, acc);
  const float4 w2 = *(const float4*)&Wa2[d0];
  float s[4];
#pragma unroll
  for (int ki = 0; ki < 4; ++ki)
    s[ki] = fmaxf(acc[ki][0], 0.f) * w2.x + fmaxf(acc[ki][1], 0.f) * w2.y +
            fmaxf(acc[ki][2], 0.f) * w2.z + fmaxf(acc[ki][3], 0.f) * w2.w;
#pragma unroll
  for (int off = 1; off < 16; off <<= 1)
#pragma unroll
    for (int ki = 0; ki < 4; ++ki) s[ki] += __shfl_xor(s[ki], off, 64);
  if ((t & 15) == 0) {
#pragma unroll
    for (int ki = 0; ki < 4; ++ki) sm.a[k0 + ki] = s[ki];
  }
  __syncthreads();
}

__device__ inline void softmax_s(SM& sm) {
  if (threadIdx.x < D) {
    const int k = threadIdx.x;
    float val = (k < KP) ? sm.a[k] : -1e30f;
    float m = val;
#pragma unroll
    for (int o = 1; o < 64; o <<= 1) m = fmaxf(m, __shfl_xor(m, o, 64));
    float e = (k < KP) ? __expf(val - m) : 0.f;
    float sum = e;
#pragma unroll
    for (int o = 1; o < 64; o <<= 1) sum += __shfl_xor(sum, o, 64);
    sm.a[k] = e / sum;
  }
  __syncthreads();
}

// v[d] = sum_k a[k] * X[k][d], 256 threads
__device__ inline void weighted_sum(SM& sm) {
  const int t = threadIdx.x;
  const int d = t & 63, kw = t >> 6;
  float p = 0.f;
  for (int k = kw; k < KP; k += 4) p = fmaf(sm.a[k], sm.X[k * STR + d], p);
  sm.part[kw * D + d] = p;
  __syncthreads();
  if (t < D)
    sm.v[t] = sm.part[t] + sm.part[D + t] + sm.part[2 * D + t] +
              sm.part[3 * D + t];
  __syncthreads();
}

// y[d] = act(bias[d] + sum_{j<J} xin[j]*W[j][d]); 256 threads
template <int J, bool RELU>
__device__ inline void mv(SM& sm, const float* xin, float* y,
                          const float* __restrict__ W, const float* bias) {
  const int w = threadIdx.x >> 6, d = threadIdx.x & 63;
  const int JW = J / 4;
  float p = 0.f;
  const float* xw = &xin[w * JW];
  const float* Wp = &W[(w * JW) * D + d];
  for (int j = 0; j < JW; ++j) {
    p = fmaf(xw[j], *Wp, p);
    Wp += D;
  }
  sm.part[w * D + d] = p;
  __syncthreads();
  if (threadIdx.x < D) {
    float s = bias[d] + sm.part[d] + sm.part[D + d] + sm.part[2 * D + d] +
              sm.part[3 * D + d];
    y[d] = RELU ? fmaxf(s, 0.f) : s;
  }
  __syncthreads();
}

// X[k][j] = src[idx[k]*D + j] (coalesced global, conflict-free LDS)
__device__ inline void load_rows(SM& sm, const float* __restrict__ src,
                                 const int* idx, int n) {
  const int j = threadIdx.x & 63, kw = threadIdx.x >> 6;
  for (int k = kw; k < n; k += 4) sm.X[k * STR + j] = src[idx[k] * D + j];
}

// ---------------- kernel 0: opinion tables op[r] = opinion_emb[r] @ Wg[64:] -----
__global__ __launch_bounds__(64) void k_op(const float* opinion_emb,
                                           const float* ia_Wg, const float* ua_Wg,
                                           float* op_ia, float* op_ua) {
  const int r = blockIdx.x % 5;
  const bool ua = blockIdx.x >= 5;
  const float* Wg = ua ? ua_Wg : ia_Wg;
  float* o = ua ? op_ua : op_ia;
  const int d = threadIdx.x;
  float acc = 0.f;
  for (int j = 0; j < D; ++j)
    acc = fmaf(opinion_emb[r * D + j], Wg[(D + j) * D + d], acc);
  o[r * D + d] = acc;
}

// ---------------- kernel 1: h_I_all for every user ------------------------------
__global__ __launch_bounds__(256, 6) void k_hIall(
    const int* C, const int* Rm, const float* user_emb, const float* item_emb,
    const float* ia_Wg, const float* ia_bg, const float* ia_Wa1,
    const float* ia_ba1, const float* ia_Wa2, const float* ia_W,
    const float* ia_b, const float* op_ia, float* h_I_all) {
  __shared__ SM sm;
  const int u = blockIdx.x;
  const int t = threadIdx.x;
  if (t < KP) {
    int c = C[u * KP + t];
    sm.ci[t] = c;
    sm.rk[t] = Rm[u * NITEMS + c];
  }
  if (t < D) {
    sm.ctx[t] = user_emb[u * D + t];
    sm.init[t] = ia_bg[t];
  }
  __syncthreads();
  load_rows(sm, item_emb, sm.ci, KP);
  __syncthreads();
  gate_mm_inplace(sm, ia_Wg, op_ia);                          // X <- x rows
  mv<D, false>(sm, sm.ctx, sm.init, &ia_Wa1[D * D], ia_ba1);  // init = ba1 + ctx@Wa1hi
  att_mm(sm, ia_Wa1, ia_Wa2);
  softmax_s(sm);
  weighted_sum(sm);
  mv<D, true>(sm, sm.v, sm.buf0, ia_W, ia_b);
  if (t < D) h_I_all[u * D + t] = sm.buf0[t];
}

// ---------------- kernel 2: h_S (social aggregation) ----------------------------
__global__ __launch_bounds__(256, 6) void k_hS(
    const int* user_idx, const int* Nn, const float* user_emb,
    const float* sa_Wa1, const float* sa_ba1, const float* sa_Wa2,
    const float* sa_W, const float* sa_b, const float* h_I_all, float* h_S) {
  __shared__ SM sm;
  const int b = blockIdx.x, t = threadIdx.x;
  const int u = user_idx[b];
  if (t < KP) sm.ci[t] = Nn[u * KP + t];
  if (t < D) sm.ctx[t] = user_emb[u * D + t];
  __syncthreads();
  load_rows(sm, h_I_all, sm.ci, KP);
  mv<D, false>(sm, sm.ctx, sm.init, &sa_Wa1[D * D], sa_ba1);  // has internal syncs
  att_mm(sm, sa_Wa1, sa_Wa2);
  softmax_s(sm);
  weighted_sum(sm);
  mv<D, true>(sm, sm.v, sm.buf0, sa_W, sa_b);
  if (t < D) h_S[b * D + t] = sm.buf0[t];
}

// ---------------- kernel 3: z (item-side agg) + fu/rp MLPs → output -------------
__global__ __launch_bounds__(256, 6) void k_z_mlp(
    const int* user_idx, const int* item_idx, const int* Bm, const int* Rm,
    const float* user_emb, const float* item_emb, const float* ua_Wg,
    const float* ua_bg, const float* ua_Wa1, const float* ua_ba1,
    const float* ua_Wa2, const float* ua_W, const float* ua_b,
    const float* op_ua, const float* fu_W1, const float* fu_b1,
    const float* fu_W2, const float* fu_b2, const float* fu_W3,
    const float* fu_b3, const float* rp_W1, const float* rp_b1,
    const float* rp_W2, const float* rp_b2, const float* rp_W3,
    const float* rp_b3, const float* h_I_all, const float* h_S, float* out) {
  __shared__ SM sm;
  const int b = blockIdx.x, t = threadIdx.x;
  const int it = item_idx[b];
  const int u = user_idx[b];
  if (t < KP) {
    int bn = Bm[it * KP + t];
    sm.ci[t] = bn;
    sm.rk[t] = Rm[bn * NITEMS + it];
  }
  if (t < D) {
    sm.ctx[t] = item_emb[it * D + t];
    sm.init[t] = ua_bg[t];
  }
  __syncthreads();
  load_rows(sm, user_emb, sm.ci, KP);
  __syncthreads();
  gate_mm_inplace(sm, ua_Wg, op_ua);                          // X <- f rows
  mv<D, false>(sm, sm.ctx, sm.init, &ua_Wa1[D * D], ua_ba1);
  att_mm(sm, ua_Wa1, ua_Wa2);
  softmax_s(sm);
  weighted_sum(sm);
  mv<D, true>(sm, sm.v, sm.buf1, ua_W, ua_b);                 // z in buf1
  // ---- fu MLP on concat(h_I_all[u], h_S[b]) ----
  if (t < D) {
    sm.cat[t] = h_I_all[u * D + t];
    sm.cat[D + t] = h_S[b * D + t];
  }
  __syncthreads();
  mv<2 * D, true>(sm, sm.cat, sm.buf0, fu_W1, fu_b1);
  mv<D, true>(sm, sm.buf0, sm.v, fu_W2, fu_b2);
  mv<D, true>(sm, sm.v, sm.buf0, fu_W3, fu_b3);
  // ---- rp MLP on concat(h, z) ----
  if (t < D) {
    sm.cat[t] = sm.buf0[t];
    sm.cat[D + t] = sm.buf1[t];
  }
  __syncthreads();
  mv<2 * D, true>(sm, sm.cat, sm.buf0, rp_W1, rp_b1);
  mv<D, true>(sm, sm.buf0, sm.v, rp_W2, rp_b2);
  if (t < D) {
    float p = sm.v[t] * rp_W3[t];
#pragma unroll
    for (int o = 1; o < 64; o <<= 1) p += __shfl_xor(p, o, 64);
    if (t == 0) out[b] = p + rp_b3[0];
  }
}

extern "C" void kernel_launch(void* const* d_in, const int* in_sizes, int n_in,
                              void* d_out, int out_size, void* d_ws,
                              size_t ws_size, hipStream_t stream) {
  const int* user_idx = (const int*)d_in[0];
  const int* item_idx = (const int*)d_in[1];
  const int* C = (const int*)d_in[2];
  const int* Nn = (const int*)d_in[3];
  const int* Bm = (const int*)d_in[4];
  const int* Rm = (const int*)d_in[5];
  const float* user_emb = (const float*)d_in[6];
  const float* item_emb = (const float*)d_in[7];
  const float* opinion_emb = (const float*)d_in[8];
  const float* ia_Wg = (const float*)d_in[9];
  const float* ia_bg = (const float*)d_in[10];
  const float* ua_Wg = (const float*)d_in[11];
  const float* ua_bg = (const float*)d_in[12];
  const float* ia_Wa1 = (const float*)d_in[13];
  const float* ia_ba1 = (const float*)d_in[14];
  const float* ia_Wa2 = (const float*)d_in[15];
  const float* ia_W = (const float*)d_in[17];
  const float* ia_b = (const float*)d_in[18];
  const float* sa_Wa1 = (const float*)d_in[19];
  const float* sa_ba1 = (const float*)d_in[20];
  const float* sa_Wa2 = (const float*)d_in[21];
  const float* sa_W = (const float*)d_in[23];
  const float* sa_b = (const float*)d_in[24];
  const float* ua_Wa1 = (const float*)d_in[25];
  const float* ua_ba1 = (const float*)d_in[26];
  const float* ua_Wa2 = (const float*)d_in[27];
  const float* ua_W = (const float*)d_in[29];
  const float* ua_b = (const float*)d_in[30];
  const float* fu_W1 = (const float*)d_in[31];
  const float* fu_b1 = (const float*)d_in[32];
  const float* fu_W2 = (const float*)d_in[33];
  const float* fu_b2 = (const float*)d_in[34];
  const float* rp_W1 = (const float*)d_in[35];
  const float* rp_b1 = (const float*)d_in[36];
  const float* rp_W2 = (const float*)d_in[37];
  const float* rp_b2 = (const float*)d_in[38];
  const float* fu_W3 = (const float*)d_in[39];
  const float* fu_b3 = (const float*)d_in[40];
  const float* rp_W3 = (const float*)d_in[41];
  const float* rp_b3 = (const float*)d_in[42];

  const int NU = in_sizes[6] / D;  // 10000 users
  const int B = in_sizes[0];       // 2048

  float* ws = (float*)d_ws;
  float* h_I_all = ws;               // NU*D
  float* h_S = ws + (size_t)NU * D;  // B*D
  float* op_ia = h_S + (size_t)B * D;
  float* op_ua = op_ia + 5 * D;

  k_op<<<10, 64, 0, stream>>>(opinion_emb, ia_Wg, ua_Wg, op_ia, op_ua);
  k_hIall<<<NU, 256, 0, stream>>>(C, Rm, user_emb, item_emb, ia_Wg, ia_bg,
                                  ia_Wa1, ia_ba1, ia_Wa2, ia_W, ia_b, op_ia,
                                  h_I_all);
  k_hS<<<B, 256, 0, stream>>>(user_idx, Nn, user_emb, sa_Wa1, sa_ba1, sa_Wa2,
                              sa_W, sa_b, h_I_all, h_S);
  k_z_mlp<<<B, 256, 0, stream>>>(user_idx, item_idx, Bm, Rm, user_emb, item_emb,
                                 ua_Wg, ua_bg, ua_Wa1, ua_ba1, ua_Wa2, ua_W,
                                 ua_b, op_ua, fu_W1, fu_b1, fu_W2, fu_b2, fu_W3,
                                 fu_b3, rp_W1, rp_b1, rp_W2, rp_b2, rp_W3,
                                 rp_b3, h_I_all, h_S, (float*)d_out);
}

// Round 3
// 220.659 us; speedup vs baseline: 1.5969x; 1.2758x over previous
//
#include <hip/hip_runtime.h>

#define D 64
#define KP 50          // neighbors per row
#define STR 68         // padded LDS row stride (floats): 17 x 16B -> conflict-free
#define NITEMS 10000   // R row stride

struct SM {
  float X[KP * STR];   // row-major X[k][j]; gate output written in place
  float init[D];       // per-d init (bias / bias + ctx@Wa1hi)
  float ctx[D];
  float a[D];          // softmax weights
  float v[D];          // attention-weighted sum
  float buf0[D];
  float buf1[D];
  float cat[2 * D];
  float part[4 * D];   // partials (matvec / att-score / weighted-sum)
  int   ci[KP];
  int   rk[KP];
};

// acc[dd] += sum_j Xr[j] * Wp[j*D + dd]   (Wp wave-uniform -> s_load + SGPR FMA)
__device__ inline void mm16(const float* Xr, const float* __restrict__ Wp,
                            float acc[16]) {
  for (int j4 = 0; j4 < D; j4 += 4) {
    float4 xv = *(const float4*)&Xr[j4];
    const float xr[4] = {xv.x, xv.y, xv.z, xv.w};
#pragma unroll
    for (int jj = 0; jj < 4; ++jj) {
#pragma unroll
      for (int dd = 0; dd < 16; ++dd)
        acc[dd] = fmaf(xr[jj], Wp[(j4 + jj) * D + dd], acc[dd]);
    }
  }
}

// X <- relu(init + op[rk[k]] + X @ W), in place. lane = k, wave owns 16 d's.
__device__ inline void gate_mm(SM& sm, const float* __restrict__ W,
                               const float* __restrict__ oprow) {
  const int t = threadIdx.x, lane = t & 63;
  const int k = lane < KP ? lane : KP - 1;
  const int dwu = __builtin_amdgcn_readfirstlane((t >> 6) << 4);
  const int rkk = sm.rk[k];
  const float* op = &oprow[rkk * D + dwu];
  float acc[16];
#pragma unroll
  for (int dd4 = 0; dd4 < 16; dd4 += 4) {
    float4 ov = *(const float4*)&op[dd4];
    acc[dd4 + 0] = sm.init[dwu + dd4 + 0] + ov.x;
    acc[dd4 + 1] = sm.init[dwu + dd4 + 1] + ov.y;
    acc[dd4 + 2] = sm.init[dwu + dd4 + 2] + ov.z;
    acc[dd4 + 3] = sm.init[dwu + dd4 + 3] + ov.w;
  }
  mm16(&sm.X[k * STR], &W[dwu], acc);
  __syncthreads();   // all reads of X complete
  if (lane < KP) {
#pragma unroll
    for (int dd4 = 0; dd4 < 16; dd4 += 4) {
      float4 o;
      o.x = fmaxf(acc[dd4 + 0], 0.f);
      o.y = fmaxf(acc[dd4 + 1], 0.f);
      o.z = fmaxf(acc[dd4 + 2], 0.f);
      o.w = fmaxf(acc[dd4 + 3], 0.f);
      *(float4*)&sm.X[k * STR + dwu + dd4] = o;
    }
  }
  __syncthreads();
}

// scores + softmax -> sm.a[k].  h never materialized (ba2 softmax-invariant).
__device__ inline void att_softmax(SM& sm, const float* __restrict__ Wa1,
                                   const float* __restrict__ Wa2) {
  const int t = threadIdx.x, lane = t & 63;
  const int k = lane < KP ? lane : KP - 1;
  const int dwu = __builtin_amdgcn_readfirstlane((t >> 6) << 4);
  float acc[16];
#pragma unroll
  for (int dd = 0; dd < 16; ++dd) acc[dd] = sm.init[dwu + dd];
  mm16(&sm.X[k * STR], &Wa1[dwu], acc);
  const float* __restrict__ W2 = &Wa2[dwu];
  float s = 0.f;
#pragma unroll
  for (int dd = 0; dd < 16; ++dd) s = fmaf(fmaxf(acc[dd], 0.f), W2[dd], s);
  sm.part[(t >> 6) * D + lane] = s;
  __syncthreads();
  float val = sm.part[lane] + sm.part[D + lane] + sm.part[2 * D + lane] +
              sm.part[3 * D + lane];
  val = (lane < KP) ? val : -1e30f;
  float m = val;
#pragma unroll
  for (int o = 1; o < 64; o <<= 1) m = fmaxf(m, __shfl_xor(m, o, 64));
  float e = (lane < KP) ? __expf(val - m) : 0.f;
  float ssum = e;
#pragma unroll
  for (int o = 1; o < 64; o <<= 1) ssum += __shfl_xor(ssum, o, 64);
  if (t < D) sm.a[lane] = e / ssum;
  __syncthreads();
}

// v[d] = sum_k a[k] * X[k][d], 256 threads
__device__ inline void weighted_sum(SM& sm) {
  const int t = threadIdx.x;
  const int d = t & 63, kw = t >> 6;
  float p = 0.f;
  for (int k = kw; k < KP; k += 4) p = fmaf(sm.a[k], sm.X[k * STR + d], p);
  sm.part[kw * D + d] = p;
  __syncthreads();
  if (t < D)
    sm.v[t] = sm.part[t] + sm.part[D + t] + sm.part[2 * D + t] +
              sm.part[3 * D + t];
  __syncthreads();
}

// y[d] = act(bias[d] + sum_{j<J} xin[j]*W[j][d]); 256 threads
template <int J, bool RELU>
__device__ inline void mv(SM& sm, const float* xin, float* y,
                          const float* __restrict__ W, const float* bias) {
  const int w = threadIdx.x >> 6, d = threadIdx.x & 63;
  const int JW = J / 4;
  float p = 0.f;
  const float* xw = &xin[w * JW];
  const float* Wp = &W[(w * JW) * D + d];
  for (int j = 0; j < JW; ++j) {
    p = fmaf(xw[j], *Wp, p);
    Wp += D;
  }
  sm.part[w * D + d] = p;
  __syncthreads();
  if (threadIdx.x < D) {
    float s = bias[d] + sm.part[d] + sm.part[D + d] + sm.part[2 * D + d] +
              sm.part[3 * D + d];
    y[d] = RELU ? fmaxf(s, 0.f) : s;
  }
  __syncthreads();
}

// X[k][j] = src[idx[k]*D + j] (coalesced global, conflict-free LDS)
__device__ inline void load_rows(SM& sm, const float* __restrict__ src,
                                 const int* idx, int n) {
  const int j = threadIdx.x & 63, kw = threadIdx.x >> 6;
  for (int k = kw; k < n; k += 4) sm.X[k * STR + j] = src[idx[k] * D + j];
}

// ---------------- kernel 0: opinion tables op[r] = opinion_emb[r] @ Wg[64:] -----
__global__ __launch_bounds__(64) void k_op(const float* opinion_emb,
                                           const float* ia_Wg, const float* ua_Wg,
                                           float* op_ia, float* op_ua) {
  const int r = blockIdx.x % 5;
  const bool ua = blockIdx.x >= 5;
  const float* Wg = ua ? ua_Wg : ia_Wg;
  float* o = ua ? op_ua : op_ia;
  const int d = threadIdx.x;
  float acc = 0.f;
  for (int j = 0; j < D; ++j)
    acc = fmaf(opinion_emb[r * D + j], Wg[(D + j) * D + d], acc);
  o[r * D + d] = acc;
}

// ---------------- kernel 1: h_I_all for every user ------------------------------
__global__ __launch_bounds__(256, 6) void k_hIall(
    const int* C, const int* Rm, const float* user_emb, const float* item_emb,
    const float* ia_Wg, const float* ia_bg, const float* ia_Wa1,
    const float* ia_ba1, const float* ia_Wa2, const float* ia_W,
    const float* ia_b, const float* op_ia, float* h_I_all) {
  __shared__ SM sm;
  const int u = blockIdx.x;
  const int t = threadIdx.x;
  if (t < KP) {
    int c = C[u * KP + t];
    sm.ci[t] = c;
    sm.rk[t] = Rm[u * NITEMS + c];
  }
  if (t < D) {
    sm.ctx[t] = user_emb[u * D + t];
    sm.init[t] = ia_bg[t];
  }
  __syncthreads();
  load_rows(sm, item_emb, sm.ci, KP);
  __syncthreads();
  gate_mm(sm, ia_Wg, op_ia);                                  // X <- x rows
  mv<D, false>(sm, sm.ctx, sm.init, &ia_Wa1[D * D], ia_ba1);  // init = ba1 + ctx@Wa1hi
  att_softmax(sm, ia_Wa1, ia_Wa2);
  weighted_sum(sm);
  mv<D, true>(sm, sm.v, sm.buf0, ia_W, ia_b);
  if (t < D) h_I_all[u * D + t] = sm.buf0[t];
}

// ---------------- kernel 2: h_S (social aggregation) ----------------------------
__global__ __launch_bounds__(256, 6) void k_hS(
    const int* user_idx, const int* Nn, const float* user_emb,
    const float* sa_Wa1, const float* sa_ba1, const float* sa_Wa2,
    const float* sa_W, const float* sa_b, const float* h_I_all, float* h_S) {
  __shared__ SM sm;
  const int b = blockIdx.x, t = threadIdx.x;
  const int u = user_idx[b];
  if (t < KP) sm.ci[t] = Nn[u * KP + t];
  if (t < D) sm.ctx[t] = user_emb[u * D + t];
  __syncthreads();
  load_rows(sm, h_I_all, sm.ci, KP);
  mv<D, false>(sm, sm.ctx, sm.init, &sa_Wa1[D * D], sa_ba1);  // internal barriers
  att_softmax(sm, sa_Wa1, sa_Wa2);
  weighted_sum(sm);
  mv<D, true>(sm, sm.v, sm.buf0, sa_W, sa_b);
  if (t < D) h_S[b * D + t] = sm.buf0[t];
}

// ---------------- kernel 3: z (item-side agg) + fu/rp MLPs → output -------------
__global__ __launch_bounds__(256, 6) void k_z_mlp(
    const int* user_idx, const int* item_idx, const int* Bm, const int* Rm,
    const float* user_emb, const float* item_emb, const float* ua_Wg,
    const float* ua_bg, const float* ua_Wa1, const float* ua_ba1,
    const float* ua_Wa2, const float* ua_W, const float* ua_b,
    const float* op_ua, const float* fu_W1, const float* fu_b1,
    const float* fu_W2, const float* fu_b2, const float* fu_W3,
    const float* fu_b3, const float* rp_W1, const float* rp_b1,
    const float* rp_W2, const float* rp_b2, const float* rp_W3,
    const float* rp_b3, const float* h_I_all, const float* h_S, float* out) {
  __shared__ SM sm;
  const int b = blockIdx.x, t = threadIdx.x;
  const int it = item_idx[b];
  const int u = user_idx[b];
  if (t < KP) {
    int bn = Bm[it * KP + t];
    sm.ci[t] = bn;
    sm.rk[t] = Rm[bn * NITEMS + it];
  }
  if (t < D) {
    sm.ctx[t] = item_emb[it * D + t];
    sm.init[t] = ua_bg[t];
  }
  __syncthreads();
  load_rows(sm, user_emb, sm.ci, KP);
  __syncthreads();
  gate_mm(sm, ua_Wg, op_ua);                                  // X <- f rows
  mv<D, false>(sm, sm.ctx, sm.init, &ua_Wa1[D * D], ua_ba1);
  att_softmax(sm, ua_Wa1, ua_Wa2);
  weighted_sum(sm);
  mv<D, true>(sm, sm.v, sm.buf1, ua_W, ua_b);                 // z in buf1
  // ---- fu MLP on concat(h_I_all[u], h_S[b]) ----
  if (t < D) {
    sm.cat[t] = h_I_all[u * D + t];
    sm.cat[D + t] = h_S[b * D + t];
  }
  __syncthreads();
  mv<2 * D, true>(sm, sm.cat, sm.buf0, fu_W1, fu_b1);
  mv<D, true>(sm, sm.buf0, sm.v, fu_W2, fu_b2);
  mv<D, true>(sm, sm.v, sm.buf0, fu_W3, fu_b3);
  // ---- rp MLP on concat(h, z) ----
  if (t < D) {
    sm.cat[t] = sm.buf0[t];
    sm.cat[D + t] = sm.buf1[t];
  }
  __syncthreads();
  mv<2 * D, true>(sm, sm.cat, sm.buf0, rp_W1, rp_b1);
  mv<D, true>(sm, sm.buf0, sm.v, rp_W2, rp_b2);
  if (t < D) {
    float p = sm.v[t] * rp_W3[t];
#pragma unroll
    for (int o = 1; o < 64; o <<= 1) p += __shfl_xor(p, o, 64);
    if (t == 0) out[b] = p + rp_b3[0];
  }
}

extern "C" void kernel_launch(void* const* d_in, const int* in_sizes, int n_in,
                              void* d_out, int out_size, void* d_ws,
                              size_t ws_size, hipStream_t stream) {
  const int* user_idx = (const int*)d_in[0];
  const int* item_idx = (const int*)d_in[1];
  const int* C = (const int*)d_in[2];
  const int* Nn = (const int*)d_in[3];
  const int* Bm = (const int*)d_in[4];
  const int* Rm = (const int*)d_in[5];
  const float* user_emb = (const float*)d_in[6];
  const float* item_emb = (const float*)d_in[7];
  const float* opinion_emb = (const float*)d_in[8];
  const float* ia_Wg = (const float*)d_in[9];
  const float* ia_bg = (const float*)d_in[10];
  const float* ua_Wg = (const float*)d_in[11];
  const float* ua_bg = (const float*)d_in[12];
  const float* ia_Wa1 = (const float*)d_in[13];
  const float* ia_ba1 = (const float*)d_in[14];
  const float* ia_Wa2 = (const float*)d_in[15];
  const float* ia_W = (const float*)d_in[17];
  const float* ia_b = (const float*)d_in[18];
  const float* sa_Wa1 = (const float*)d_in[19];
  const float* sa_ba1 = (const float*)d_in[20];
  const float* sa_Wa2 = (const float*)d_in[21];
  const float* sa_W = (const float*)d_in[23];
  const float* sa_b = (const float*)d_in[24];
  const float* ua_Wa1 = (const float*)d_in[25];
  const float* ua_ba1 = (const float*)d_in[26];
  const float* ua_Wa2 = (const float*)d_in[27];
  const float* ua_W = (const float*)d_in[29];
  const float* ua_b = (const float*)d_in[30];
  const float* fu_W1 = (const float*)d_in[31];
  const float* fu_b1 = (const float*)d_in[32];
  const float* fu_W2 = (const float*)d_in[33];
  const float* fu_b2 = (const float*)d_in[34];
  const float* rp_W1 = (const float*)d_in[35];
  const float* rp_b1 = (const float*)d_in[36];
  const float* rp_W2 = (const float*)d_in[37];
  const float* rp_b2 = (const float*)d_in[38];
  const float* fu_W3 = (const float*)d_in[39];
  const float* fu_b3 = (const float*)d_in[40];
  const float* rp_W3 = (const float*)d_in[41];
  const float* rp_b3 = (const float*)d_in[42];

  const int NU = in_sizes[6] / D;  // 10000 users
  const int B = in_sizes[0];       // 2048

  float* ws = (float*)d_ws;
  float* h_I_all = ws;               // NU*D
  float* h_S = ws + (size_t)NU * D;  // B*D
  float* op_ia = h_S + (size_t)B * D;
  float* op_ua = op_ia + 5 * D;

  k_op<<<10, 64, 0, stream>>>(opinion_emb, ia_Wg, ua_Wg, op_ia, op_ua);
  k_hIall<<<NU, 256, 0, stream>>>(C, Rm, user_emb, item_emb, ia_Wg, ia_bg,
                                  ia_Wa1, ia_ba1, ia_Wa2, ia_W, ia_b, op_ia,
                                  h_I_all);
  k_hS<<<B, 256, 0, stream>>>(user_idx, Nn, user_emb, sa_Wa1, sa_ba1, sa_Wa2,
                              sa_W, sa_b, h_I_all, h_S);
  k_z_mlp<<<B, 256, 0, stream>>>(user_idx, item_idx, Bm, Rm, user_emb, item_emb,
                                 ua_Wg, ua_bg, ua_Wa1, ua_ba1, ua_Wa2, ua_W,
                                 ua_b, op_ua, fu_W1, fu_b1, fu_W2, fu_b2, fu_W3,
                                 fu_b3, rp_W1, rp_b1, rp_W2, rp_b2, rp_W3,
                                 rp_b3, h_I_all, h_S, (float*)d_out);
}